// Round 7
// baseline (175.397 us; speedup 1.0000x reference)
//
#include <hip/hip_runtime.h>
#include <hip/hip_fp16.h>

// DecompGrid, round 7: fp16 channel-last tables + cheap z-only counting sort
// (64 buckets: LDS hist -> 1-block offsets -> single-pass LDS-rank scatter)
// + XCD-chunked sorted sampler with NON-TEMPORAL out/sx/sidx stores (keep the
// 125MB write stream from evicting the L2 gather window).

#define GLO 63
#define GN  65
#define PLO 127
#define PN  129
#define NZB 64     // z-buckets
#define NBLK 256   // sort blocks

static constexpr size_t SUBG_H = (size_t)GN * GN * GN * 16;  // halves
static constexpr size_t SUBP_H = (size_t)PN * PN * 16;
static constexpr size_t SUBL_H = 64 * 16;
static constexpr size_t WS_HALVES = SUBG_H + 3 * SUBP_H + SUBL_H;

static inline size_t align256(size_t x) { return (x + 255) & ~(size_t)255; }

typedef float f32x4 __attribute__((ext_vector_type(4)));

struct Axis { int base; float u0, u1; };

__device__ __forceinline__ Axis make_axis(float p, int size) {
    float f  = floorf(p);
    float w  = p - f;
    float fs = (float)(size - 1);
    int i0 = (int)fminf(fmaxf(f,        0.0f), fs);
    int i1 = (int)fminf(fmaxf(f + 1.0f, 0.0f), fs);
    int base = (i0 <= size - 2) ? i0 : (size - 2);
    Axis a;
    a.base = base;
    float w0 = 1.0f - w;
    a.u0 = (i0 == base ? w0 : 0.0f) + (i1 == base ? w : 0.0f);
    a.u1 = (i0 == base ? 0.0f : w0) + (i1 == base ? 0.0f : w);
    return a;
}

__device__ __forceinline__ int zbucket(float z) {
    int gz = (int)floorf((z + 1.0f) * 0.5f * 127.0f);
    return min(max(gz - GLO, 0), GN - 2);   // 0..63
}

struct f8 { float v[8]; };

__device__ __forceinline__ f8 load8h(const __half* p) {
    float4 r = *reinterpret_cast<const float4*>(p);
    union { float4 f; __half2 h[4]; } u; u.f = r;
    f8 o;
    #pragma unroll
    for (int i = 0; i < 4; ++i) {
        float2 t = __half22float2(u.h[i]);
        o.v[2 * i] = t.x; o.v[2 * i + 1] = t.y;
    }
    return o;
}

__device__ __forceinline__ f8 lerp_pair(const __half* p, float u0, float u1) {
    f8 a = load8h(p), b = load8h(p + 16);
    f8 o;
    #pragma unroll
    for (int j = 0; j < 8; ++j) o.v[j] = fmaf(a.v[j], u0, b.v[j] * u1);
    return o;
}

__device__ __forceinline__ void sample_point(
    float px, float py, float pz, float pw,
    const __half* __restrict__ ws, int c8, f8& spatial, f8& param)
{
    Axis gx = make_axis((px + 1.0f) * 0.5f * 127.0f, 128);
    Axis gy = make_axis((py + 1.0f) * 0.5f * 127.0f, 128);
    Axis gz = make_axis((pz + 1.0f) * 0.5f * 127.0f, 128);
    Axis q0 = make_axis((px + 1.0f) * 0.5f * 255.0f, 256);
    Axis q1 = make_axis((py + 1.0f) * 0.5f * 255.0f, 256);
    Axis q2 = make_axis((pz + 1.0f) * 0.5f * 255.0f, 256);
    Axis lx = make_axis(pw * 63.0f, 64);

    int gxb = min(max(gx.base - GLO, 0), GN - 2);
    int gyb = min(max(gy.base - GLO, 0), GN - 2);
    int gzb = min(max(gz.base - GLO, 0), GN - 2);
    int c0b = min(max(q0.base - PLO, 0), PN - 2);
    int c1b = min(max(q1.base - PLO, 0), PN - 2);
    int c2b = min(max(q2.base - PLO, 0), PN - 2);

    const __half* g = ws + (((size_t)gzb * GN + gyb) * GN + gxb) * 16 + c8;
    const size_t YS = (size_t)GN * 16, ZS = (size_t)GN * GN * 16;
    float w00 = gz.u0 * gy.u0, w01 = gz.u0 * gy.u1;
    float w10 = gz.u1 * gy.u0, w11 = gz.u1 * gy.u1;
    f8 e0 = lerp_pair(g,           gx.u0, gx.u1);
    f8 e1 = lerp_pair(g + YS,      gx.u0, gx.u1);
    f8 e2 = lerp_pair(g + ZS,      gx.u0, gx.u1);
    f8 e3 = lerp_pair(g + ZS + YS, gx.u0, gx.u1);
    f8 tri;
    #pragma unroll
    for (int j = 0; j < 8; ++j)
        tri.v[j] = fmaf(e3.v[j], w11, fmaf(e2.v[j], w10,
                   fmaf(e1.v[j], w01, e0.v[j] * w00)));

    const __half* P0 = ws + SUBG_H;
    const __half* P1 = P0 + SUBP_H;
    const __half* P2 = P1 + SUBP_H;
    const size_t RS = (size_t)PN * 16;

    const __half* pa = P0 + ((size_t)c2b * PN + c1b) * 16 + c8;
    f8 r0 = lerp_pair(pa,      q1.u0, q1.u1);
    f8 r1 = lerp_pair(pa + RS, q1.u0, q1.u1);
    const __half* pb = P1 + ((size_t)c2b * PN + c0b) * 16 + c8;
    f8 s0 = lerp_pair(pb,      q0.u0, q0.u1);
    f8 s1 = lerp_pair(pb + RS, q0.u0, q0.u1);
    const __half* pc = P2 + ((size_t)c1b * PN + c0b) * 16 + c8;
    f8 t0 = lerp_pair(pc,      q0.u0, q0.u1);
    f8 t1 = lerp_pair(pc + RS, q0.u0, q0.u1);
    const __half* lp = P2 + SUBP_H + (size_t)lx.base * 16 + c8;
    param = lerp_pair(lp, lx.u0, lx.u1);

    #pragma unroll
    for (int j = 0; j < 8; ++j) {
        float v0 = fmaf(r0.v[j], q2.u0, r1.v[j] * q2.u1);
        float v1 = fmaf(s0.v[j], q2.u0, s1.v[j] * q2.u1);
        float v2 = fmaf(t0.v[j], q1.u0, t1.v[j] * q1.u1);
        spatial.v[j] = tri.v[j] * v0 * v1 * v2;
    }
}

// ---------------- re-layout: f32 inputs -> fp16 channel-last ws ----------------
__global__ __launch_bounds__(256) void relayout_kernel(
    const float* __restrict__ grid3d, const float* __restrict__ p0,
    const float* __restrict__ p1, const float* __restrict__ p2,
    const float* __restrict__ line0, __half* __restrict__ ws)
{
    int idx = blockIdx.x * blockDim.x + threadIdx.x;
    int c = idx & 15;
    int t = idx >> 4;
    const int GT = GN * GN * GN;
    const int PT = PN * PN;
    if (t < GT) {
        int xx = t % GN; int t2 = t / GN;
        int yy = t2 % GN; int zz = t2 / GN;
        ws[idx] = __float2half(grid3d[c * (128 * 128 * 128)
                    + (GLO + zz) * (128 * 128) + (GLO + yy) * 128 + (GLO + xx)]);
        return;
    }
    t -= GT;
    __half* wp = ws + SUBG_H;
    if (t < 3 * PT) {
        int pl = t / PT; int u = t - pl * PT;
        int cc = u % PN; int r = u / PN;
        const float* src = pl == 0 ? p0 : (pl == 1 ? p1 : p2);
        wp[(size_t)pl * SUBP_H + (size_t)u * 16 + c] =
            __float2half(src[c * 65536 + (PLO + r) * 256 + (PLO + cc)]);
        return;
    }
    t -= 3 * PT;
    if (t < 64) {
        wp[3 * SUBP_H + t * 16 + c] = __float2half(line0[c * 64 + t]);
    }
}

// ---------------- z-sort: hist -> offsets -> scatter ----------------
// ghist layout: [bucket][block]  (bucket-major for coalesced offsets pass)
__global__ __launch_bounds__(256) void hist_kernel(
    const float4* __restrict__ x, int* __restrict__ ghist, int N, int chunk)
{
    __shared__ int lh[NZB];
    int blk = blockIdx.x, tid = threadIdx.x;
    if (tid < NZB) lh[tid] = 0;
    __syncthreads();
    int lo = blk * chunk, hi = min(lo + chunk, N);
    for (int i = lo + tid; i < hi; i += 256)
        atomicAdd(&lh[zbucket(x[i].z)], 1);
    __syncthreads();
    if (tid < NZB) ghist[tid * NBLK + blk] = lh[tid];
}

// 1 block, 64 threads: per-bucket totals -> exclusive scan -> per-(bucket,blk) base
__global__ __launch_bounds__(64) void offsets_kernel(
    const int* __restrict__ ghist, int* __restrict__ gbase)
{
    __shared__ int tot[NZB];
    int b = threadIdx.x;
    const int* row = ghist + b * NBLK;
    int s = 0;
    #pragma unroll 4
    for (int k = 0; k < NBLK; k += 4) {
        int4 v = *reinterpret_cast<const int4*>(row + k);
        s += v.x + v.y + v.z + v.w;
    }
    tot[b] = s;
    __syncthreads();
    if (b == 0) {
        int acc = 0;
        for (int k = 0; k < NZB; ++k) { int t = tot[k]; tot[k] = acc; acc += t; }
    }
    __syncthreads();
    int run = tot[b];
    int* orow = gbase + b * NBLK;
    for (int k = 0; k < NBLK; ++k) { int v = row[k]; orow[k] = run; run += v; }
}

__global__ __launch_bounds__(256) void scatter_kernel(
    const float4* __restrict__ x, const int* __restrict__ gbase,
    float4* __restrict__ sx, int* __restrict__ sidx, int N, int chunk)
{
    __shared__ int lh[NZB];
    __shared__ int base[NZB];
    int blk = blockIdx.x, tid = threadIdx.x;
    if (tid < NZB) { lh[tid] = 0; base[tid] = gbase[tid * NBLK + blk]; }
    __syncthreads();
    int lo = blk * chunk, hi = min(lo + chunk, N);
    for (int i = lo + tid; i < hi; i += 256) {
        float4 xv = x[i];
        int b = zbucket(xv.z);
        int rank = atomicAdd(&lh[b], 1);      // LDS atomic, uncontended
        int pos = base[b] + rank;
        f32x4 v; v.x = xv.x; v.y = xv.y; v.z = xv.z; v.w = xv.w;
        __builtin_nontemporal_store(v, reinterpret_cast<f32x4*>(sx + pos));
        __builtin_nontemporal_store(i, sidx + pos);
    }
}

// ---------------- sampler over sorted points, XCD-chunked, nt stores ----------------
__global__ __launch_bounds__(256) void sample_sorted_kernel(
    const float4* __restrict__ sx, const int* __restrict__ sidx,
    const __half* __restrict__ ws, float* __restrict__ out, int N)
{
    // bijective XCD swizzle (m204): contiguous sorted chunks per XCD
    int nb = gridDim.x;
    int obid = blockIdx.x;
    int q = nb >> 3, r = nb & 7;
    int xcd = obid & 7, seq = obid >> 3;
    int bid = (xcd < r ? xcd * (q + 1) : r * (q + 1) + (xcd - r) * q) + seq;

    int li = bid * 128 + (threadIdx.x >> 1);
    if (li >= N) return;
    int c8 = (threadIdx.x & 1) * 8;

    f32x4 xv = __builtin_nontemporal_load(reinterpret_cast<const f32x4*>(sx + li));
    int n = __builtin_nontemporal_load(sidx + li);

    f8 spatial, param;
    sample_point(xv.x, xv.y, xv.z, xv.w, ws, c8, spatial, param);

    float* o = out + (size_t)n * 32 + c8;
    f32x4 a, b, c, d;
    a.x = spatial.v[0]; a.y = spatial.v[1]; a.z = spatial.v[2]; a.w = spatial.v[3];
    b.x = spatial.v[4]; b.y = spatial.v[5]; b.z = spatial.v[6]; b.w = spatial.v[7];
    c.x = param.v[0];   c.y = param.v[1];   c.z = param.v[2];   c.w = param.v[3];
    d.x = param.v[4];   d.y = param.v[5];   d.z = param.v[6];   d.w = param.v[7];
    __builtin_nontemporal_store(a, reinterpret_cast<f32x4*>(o));
    __builtin_nontemporal_store(b, reinterpret_cast<f32x4*>(o + 4));
    __builtin_nontemporal_store(c, reinterpret_cast<f32x4*>(o + 16));
    __builtin_nontemporal_store(d, reinterpret_cast<f32x4*>(o + 20));
}

// ---------------- fallback: unsorted sampler ----------------
__global__ __launch_bounds__(256) void sample_unsorted_kernel(
    const float* __restrict__ x, const __half* __restrict__ ws,
    float* __restrict__ out, int N)
{
    int gid = blockIdx.x * blockDim.x + threadIdx.x;
    int n = gid >> 1;
    if (n >= N) return;
    int c8 = (gid & 1) * 8;
    float4 xv = reinterpret_cast<const float4*>(x)[n];
    f8 spatial, param;
    sample_point(xv.x, xv.y, xv.z, xv.w, ws, c8, spatial, param);
    float* o = out + (size_t)n * 32 + c8;
    *reinterpret_cast<float4*>(o) =
        make_float4(spatial.v[0], spatial.v[1], spatial.v[2], spatial.v[3]);
    *reinterpret_cast<float4*>(o + 4) =
        make_float4(spatial.v[4], spatial.v[5], spatial.v[6], spatial.v[7]);
    *reinterpret_cast<float4*>(o + 16) =
        make_float4(param.v[0], param.v[1], param.v[2], param.v[3]);
    *reinterpret_cast<float4*>(o + 20) =
        make_float4(param.v[4], param.v[5], param.v[6], param.v[7]);
}

// ---------------- last-resort direct kernel (no ws) ----------------
__global__ __launch_bounds__(256) void direct_kernel(
    const float* __restrict__ x,
    const float* __restrict__ grid3d, const float* __restrict__ p0,
    const float* __restrict__ p1, const float* __restrict__ p2,
    const float* __restrict__ line0, float* __restrict__ out, int N)
{
    int n = blockIdx.x * blockDim.x + threadIdx.x;
    if (n >= N) return;
    float4 xv = reinterpret_cast<const float4*>(x)[n];
    Axis gx = make_axis((xv.x + 1.0f) * 0.5f * 127.0f, 128);
    Axis gy = make_axis((xv.y + 1.0f) * 0.5f * 127.0f, 128);
    Axis gz = make_axis((xv.z + 1.0f) * 0.5f * 127.0f, 128);
    Axis q0 = make_axis((xv.x + 1.0f) * 0.5f * 255.0f, 256);
    Axis q1 = make_axis((xv.y + 1.0f) * 0.5f * 255.0f, 256);
    Axis q2 = make_axis((xv.z + 1.0f) * 0.5f * 255.0f, 256);
    Axis lx = make_axis(xv.w * 63.0f, 64);
    const int GS = 128 * 128 * 128, PS = 256 * 256, ZS = 128 * 128;
    int gb  = (gz.base * 128 + gy.base) * 128 + gx.base;
    int b0b = q2.base * 256 + q1.base;
    int b1b = q2.base * 256 + q0.base;
    int b2b = q1.base * 256 + q0.base;
    float res[32];
    #pragma unroll
    for (int c = 0; c < 16; ++c) {
        const float* g = grid3d + c * GS + gb;
        float d00 = g[0]        * gx.u0 + g[1]        * gx.u1;
        float d01 = g[128]      * gx.u0 + g[129]      * gx.u1;
        float d10 = g[ZS]       * gx.u0 + g[ZS + 1]   * gx.u1;
        float d11 = g[ZS + 128] * gx.u0 + g[ZS + 129] * gx.u1;
        float tri = gz.u0 * (gy.u0 * d00 + gy.u1 * d01)
                  + gz.u1 * (gy.u0 * d10 + gy.u1 * d11);
        const float* a = p0 + c * PS + b0b;
        float v0 = q2.u0 * (a[0] * q1.u0 + a[1] * q1.u1)
                 + q2.u1 * (a[256] * q1.u0 + a[257] * q1.u1);
        const float* b = p1 + c * PS + b1b;
        float v1 = q2.u0 * (b[0] * q0.u0 + b[1] * q0.u1)
                 + q2.u1 * (b[256] * q0.u0 + b[257] * q0.u1);
        const float* d = p2 + c * PS + b2b;
        float v2 = q1.u0 * (d[0] * q0.u0 + d[1] * q0.u1)
                 + q1.u1 * (d[256] * q0.u0 + d[257] * q0.u1);
        const float* ln = line0 + c * 64 + lx.base;
        res[16 + c] = ln[0] * lx.u0 + ln[1] * lx.u1;
        res[c]      = tri * v0 * v1 * v2;
    }
    float4* o4 = reinterpret_cast<float4*>(out + (size_t)n * 32);
    #pragma unroll
    for (int i = 0; i < 8; ++i)
        o4[i] = make_float4(res[i*4], res[i*4+1], res[i*4+2], res[i*4+3]);
}

extern "C" void kernel_launch(void* const* d_in, const int* in_sizes, int n_in,
                              void* d_out, int out_size, void* d_ws, size_t ws_size,
                              hipStream_t stream) {
    const float* x      = (const float*)d_in[0];
    const float* grid3d = (const float*)d_in[1];
    const float* p0     = (const float*)d_in[2];
    const float* p1     = (const float*)d_in[3];
    const float* p2     = (const float*)d_in[4];
    const float* line0  = (const float*)d_in[5];
    float* out = (float*)d_out;
    int N = in_sizes[0] / 4;

    size_t tab_off   = 0;
    size_t ghist_off = align256(WS_HALVES * sizeof(__half));
    size_t gbase_off = ghist_off + (size_t)NZB * NBLK * 4;
    size_t sx_off    = align256(gbase_off + (size_t)NZB * NBLK * 4);
    size_t sidx_off  = sx_off + (size_t)N * 16;
    size_t need_sort = sidx_off + (size_t)N * 4;
    size_t need_tab  = WS_HALVES * sizeof(__half);

    if (ws_size >= need_sort) {
        char* wsb = (char*)d_ws;
        __half* tab   = (__half*)(wsb + tab_off);
        int*    ghist = (int*)(wsb + ghist_off);
        int*    gbase = (int*)(wsb + gbase_off);
        float4* sxp   = (float4*)(wsb + sx_off);
        int*    sidx  = (int*)(wsb + sidx_off);
        const float4* x4 = (const float4*)x;
        int chunk = (N + NBLK - 1) / NBLK;

        relayout_kernel<<<(int)((WS_HALVES + 255) / 256), 256, 0, stream>>>(
            grid3d, p0, p1, p2, line0, tab);
        hist_kernel<<<NBLK, 256, 0, stream>>>(x4, ghist, N, chunk);
        offsets_kernel<<<1, 64, 0, stream>>>(ghist, gbase);
        scatter_kernel<<<NBLK, 256, 0, stream>>>(x4, gbase, sxp, sidx, N, chunk);
        int blocks = (N + 127) / 128;
        sample_sorted_kernel<<<blocks, 256, 0, stream>>>(sxp, sidx, tab, out, N);
    } else if (ws_size >= need_tab) {
        __half* tab = (__half*)d_ws;
        relayout_kernel<<<(int)((WS_HALVES + 255) / 256), 256, 0, stream>>>(
            grid3d, p0, p1, p2, line0, tab);
        long long tot = (long long)N * 2;
        sample_unsorted_kernel<<<(int)((tot + 255) / 256), 256, 0, stream>>>(
            x, tab, out, N);
    } else {
        direct_kernel<<<(N + 255) / 256, 256, 0, stream>>>(
            x, grid3d, p0, p1, p2, line0, out, N);
    }
}

// Round 8
// 173.626 us; speedup vs baseline: 1.0102x; 1.0102x over previous
//
#include <hip/hip_runtime.h>
#include <hip/hip_fp16.h>

// DecompGrid, round 8: fp16 channel-last tables + cheap z-only counting sort
// + XCD-chunked sorted sampler. Round 7 lesson: z-sort collapsed gather
// FETCH 292->18 MB (keep), but nt stores on `out` caused partial-line write
// amplification (158 MB, slow path) -> revert out to normal L2 write-back.

#define GLO 63
#define GN  65
#define PLO 127
#define PN  129
#define NZB 64     // z-buckets
#define NBLK 256   // sort blocks

static constexpr size_t SUBG_H = (size_t)GN * GN * GN * 16;  // halves
static constexpr size_t SUBP_H = (size_t)PN * PN * 16;
static constexpr size_t SUBL_H = 64 * 16;
static constexpr size_t WS_HALVES = SUBG_H + 3 * SUBP_H + SUBL_H;

static inline size_t align256(size_t x) { return (x + 255) & ~(size_t)255; }

typedef float f32x4 __attribute__((ext_vector_type(4)));

struct Axis { int base; float u0, u1; };

__device__ __forceinline__ Axis make_axis(float p, int size) {
    float f  = floorf(p);
    float w  = p - f;
    float fs = (float)(size - 1);
    int i0 = (int)fminf(fmaxf(f,        0.0f), fs);
    int i1 = (int)fminf(fmaxf(f + 1.0f, 0.0f), fs);
    int base = (i0 <= size - 2) ? i0 : (size - 2);
    Axis a;
    a.base = base;
    float w0 = 1.0f - w;
    a.u0 = (i0 == base ? w0 : 0.0f) + (i1 == base ? w : 0.0f);
    a.u1 = (i0 == base ? 0.0f : w0) + (i1 == base ? 0.0f : w);
    return a;
}

__device__ __forceinline__ int zbucket(float z) {
    int gz = (int)floorf((z + 1.0f) * 0.5f * 127.0f);
    return min(max(gz - GLO, 0), GN - 2);   // 0..63
}

struct f8 { float v[8]; };

__device__ __forceinline__ f8 load8h(const __half* p) {
    float4 r = *reinterpret_cast<const float4*>(p);
    union { float4 f; __half2 h[4]; } u; u.f = r;
    f8 o;
    #pragma unroll
    for (int i = 0; i < 4; ++i) {
        float2 t = __half22float2(u.h[i]);
        o.v[2 * i] = t.x; o.v[2 * i + 1] = t.y;
    }
    return o;
}

__device__ __forceinline__ f8 lerp_pair(const __half* p, float u0, float u1) {
    f8 a = load8h(p), b = load8h(p + 16);
    f8 o;
    #pragma unroll
    for (int j = 0; j < 8; ++j) o.v[j] = fmaf(a.v[j], u0, b.v[j] * u1);
    return o;
}

__device__ __forceinline__ void sample_point(
    float px, float py, float pz, float pw,
    const __half* __restrict__ ws, int c8, f8& spatial, f8& param)
{
    Axis gx = make_axis((px + 1.0f) * 0.5f * 127.0f, 128);
    Axis gy = make_axis((py + 1.0f) * 0.5f * 127.0f, 128);
    Axis gz = make_axis((pz + 1.0f) * 0.5f * 127.0f, 128);
    Axis q0 = make_axis((px + 1.0f) * 0.5f * 255.0f, 256);
    Axis q1 = make_axis((py + 1.0f) * 0.5f * 255.0f, 256);
    Axis q2 = make_axis((pz + 1.0f) * 0.5f * 255.0f, 256);
    Axis lx = make_axis(pw * 63.0f, 64);

    int gxb = min(max(gx.base - GLO, 0), GN - 2);
    int gyb = min(max(gy.base - GLO, 0), GN - 2);
    int gzb = min(max(gz.base - GLO, 0), GN - 2);
    int c0b = min(max(q0.base - PLO, 0), PN - 2);
    int c1b = min(max(q1.base - PLO, 0), PN - 2);
    int c2b = min(max(q2.base - PLO, 0), PN - 2);

    const __half* g = ws + (((size_t)gzb * GN + gyb) * GN + gxb) * 16 + c8;
    const size_t YS = (size_t)GN * 16, ZS = (size_t)GN * GN * 16;
    float w00 = gz.u0 * gy.u0, w01 = gz.u0 * gy.u1;
    float w10 = gz.u1 * gy.u0, w11 = gz.u1 * gy.u1;
    f8 e0 = lerp_pair(g,           gx.u0, gx.u1);
    f8 e1 = lerp_pair(g + YS,      gx.u0, gx.u1);
    f8 e2 = lerp_pair(g + ZS,      gx.u0, gx.u1);
    f8 e3 = lerp_pair(g + ZS + YS, gx.u0, gx.u1);
    f8 tri;
    #pragma unroll
    for (int j = 0; j < 8; ++j)
        tri.v[j] = fmaf(e3.v[j], w11, fmaf(e2.v[j], w10,
                   fmaf(e1.v[j], w01, e0.v[j] * w00)));

    const __half* P0 = ws + SUBG_H;
    const __half* P1 = P0 + SUBP_H;
    const __half* P2 = P1 + SUBP_H;
    const size_t RS = (size_t)PN * 16;

    const __half* pa = P0 + ((size_t)c2b * PN + c1b) * 16 + c8;
    f8 r0 = lerp_pair(pa,      q1.u0, q1.u1);
    f8 r1 = lerp_pair(pa + RS, q1.u0, q1.u1);
    const __half* pb = P1 + ((size_t)c2b * PN + c0b) * 16 + c8;
    f8 s0 = lerp_pair(pb,      q0.u0, q0.u1);
    f8 s1 = lerp_pair(pb + RS, q0.u0, q0.u1);
    const __half* pc = P2 + ((size_t)c1b * PN + c0b) * 16 + c8;
    f8 t0 = lerp_pair(pc,      q0.u0, q0.u1);
    f8 t1 = lerp_pair(pc + RS, q0.u0, q0.u1);
    const __half* lp = P2 + SUBP_H + (size_t)lx.base * 16 + c8;
    param = lerp_pair(lp, lx.u0, lx.u1);

    #pragma unroll
    for (int j = 0; j < 8; ++j) {
        float v0 = fmaf(r0.v[j], q2.u0, r1.v[j] * q2.u1);
        float v1 = fmaf(s0.v[j], q2.u0, s1.v[j] * q2.u1);
        float v2 = fmaf(t0.v[j], q1.u0, t1.v[j] * q1.u1);
        spatial.v[j] = tri.v[j] * v0 * v1 * v2;
    }
}

// ---------------- re-layout: f32 inputs -> fp16 channel-last ws ----------------
__global__ __launch_bounds__(256) void relayout_kernel(
    const float* __restrict__ grid3d, const float* __restrict__ p0,
    const float* __restrict__ p1, const float* __restrict__ p2,
    const float* __restrict__ line0, __half* __restrict__ ws)
{
    int idx = blockIdx.x * blockDim.x + threadIdx.x;
    int c = idx & 15;
    int t = idx >> 4;
    const int GT = GN * GN * GN;
    const int PT = PN * PN;
    if (t < GT) {
        int xx = t % GN; int t2 = t / GN;
        int yy = t2 % GN; int zz = t2 / GN;
        ws[idx] = __float2half(grid3d[c * (128 * 128 * 128)
                    + (GLO + zz) * (128 * 128) + (GLO + yy) * 128 + (GLO + xx)]);
        return;
    }
    t -= GT;
    __half* wp = ws + SUBG_H;
    if (t < 3 * PT) {
        int pl = t / PT; int u = t - pl * PT;
        int cc = u % PN; int r = u / PN;
        const float* src = pl == 0 ? p0 : (pl == 1 ? p1 : p2);
        wp[(size_t)pl * SUBP_H + (size_t)u * 16 + c] =
            __float2half(src[c * 65536 + (PLO + r) * 256 + (PLO + cc)]);
        return;
    }
    t -= 3 * PT;
    if (t < 64) {
        wp[3 * SUBP_H + t * 16 + c] = __float2half(line0[c * 64 + t]);
    }
}

// ---------------- z-sort: hist -> offsets -> scatter ----------------
__global__ __launch_bounds__(256) void hist_kernel(
    const float4* __restrict__ x, int* __restrict__ ghist, int N, int chunk)
{
    __shared__ int lh[NZB];
    int blk = blockIdx.x, tid = threadIdx.x;
    if (tid < NZB) lh[tid] = 0;
    __syncthreads();
    int lo = blk * chunk, hi = min(lo + chunk, N);
    for (int i = lo + tid; i < hi; i += 256)
        atomicAdd(&lh[zbucket(x[i].z)], 1);
    __syncthreads();
    if (tid < NZB) ghist[tid * NBLK + blk] = lh[tid];
}

__global__ __launch_bounds__(64) void offsets_kernel(
    const int* __restrict__ ghist, int* __restrict__ gbase)
{
    __shared__ int tot[NZB];
    int b = threadIdx.x;
    const int* row = ghist + b * NBLK;
    int s = 0;
    #pragma unroll 4
    for (int k = 0; k < NBLK; k += 4) {
        int4 v = *reinterpret_cast<const int4*>(row + k);
        s += v.x + v.y + v.z + v.w;
    }
    tot[b] = s;
    __syncthreads();
    if (b == 0) {
        int acc = 0;
        for (int k = 0; k < NZB; ++k) { int t = tot[k]; tot[k] = acc; acc += t; }
    }
    __syncthreads();
    int run = tot[b];
    int* orow = gbase + b * NBLK;
    for (int k = 0; k < NBLK; ++k) { int v = row[k]; orow[k] = run; run += v; }
}

__global__ __launch_bounds__(256) void scatter_kernel(
    const float4* __restrict__ x, const int* __restrict__ gbase,
    float4* __restrict__ sx, int* __restrict__ sidx, int N, int chunk)
{
    __shared__ int lh[NZB];
    __shared__ int base[NZB];
    int blk = blockIdx.x, tid = threadIdx.x;
    if (tid < NZB) { lh[tid] = 0; base[tid] = gbase[tid * NBLK + blk]; }
    __syncthreads();
    int lo = blk * chunk, hi = min(lo + chunk, N);
    for (int i = lo + tid; i < hi; i += 256) {
        float4 xv = x[i];
        int b = zbucket(xv.z);
        int rank = atomicAdd(&lh[b], 1);      // LDS atomic, uncontended
        int pos = base[b] + rank;
        f32x4 v; v.x = xv.x; v.y = xv.y; v.z = xv.z; v.w = xv.w;
        __builtin_nontemporal_store(v, reinterpret_cast<f32x4*>(sx + pos));
        __builtin_nontemporal_store(i, sidx + pos);
    }
}

// ---------------- sampler over sorted points, XCD-chunked ----------------
__global__ __launch_bounds__(256) void sample_sorted_kernel(
    const float4* __restrict__ sx, const int* __restrict__ sidx,
    const __half* __restrict__ ws, float* __restrict__ out, int N)
{
    // bijective XCD swizzle (m204): contiguous sorted chunks per XCD
    int nb = gridDim.x;
    int obid = blockIdx.x;
    int q = nb >> 3, r = nb & 7;
    int xcd = obid & 7, seq = obid >> 3;
    int bid = (xcd < r ? xcd * (q + 1) : r * (q + 1) + (xcd - r) * q) + seq;

    int li = bid * 128 + (threadIdx.x >> 1);
    if (li >= N) return;
    int c8 = (threadIdx.x & 1) * 8;

    f32x4 xv = __builtin_nontemporal_load(reinterpret_cast<const f32x4*>(sx + li));
    int n = __builtin_nontemporal_load(sidx + li);

    f8 spatial, param;
    sample_point(xv.x, xv.y, xv.z, xv.w, ws, c8, spatial, param);

    // normal (L2 write-back) stores: scattered 128B rows coalesce in L2
    float* o = out + (size_t)n * 32 + c8;
    *reinterpret_cast<float4*>(o) =
        make_float4(spatial.v[0], spatial.v[1], spatial.v[2], spatial.v[3]);
    *reinterpret_cast<float4*>(o + 4) =
        make_float4(spatial.v[4], spatial.v[5], spatial.v[6], spatial.v[7]);
    *reinterpret_cast<float4*>(o + 16) =
        make_float4(param.v[0], param.v[1], param.v[2], param.v[3]);
    *reinterpret_cast<float4*>(o + 20) =
        make_float4(param.v[4], param.v[5], param.v[6], param.v[7]);
}

// ---------------- fallback: unsorted sampler ----------------
__global__ __launch_bounds__(256) void sample_unsorted_kernel(
    const float* __restrict__ x, const __half* __restrict__ ws,
    float* __restrict__ out, int N)
{
    int gid = blockIdx.x * blockDim.x + threadIdx.x;
    int n = gid >> 1;
    if (n >= N) return;
    int c8 = (gid & 1) * 8;
    float4 xv = reinterpret_cast<const float4*>(x)[n];
    f8 spatial, param;
    sample_point(xv.x, xv.y, xv.z, xv.w, ws, c8, spatial, param);
    float* o = out + (size_t)n * 32 + c8;
    *reinterpret_cast<float4*>(o) =
        make_float4(spatial.v[0], spatial.v[1], spatial.v[2], spatial.v[3]);
    *reinterpret_cast<float4*>(o + 4) =
        make_float4(spatial.v[4], spatial.v[5], spatial.v[6], spatial.v[7]);
    *reinterpret_cast<float4*>(o + 16) =
        make_float4(param.v[0], param.v[1], param.v[2], param.v[3]);
    *reinterpret_cast<float4*>(o + 20) =
        make_float4(param.v[4], param.v[5], param.v[6], param.v[7]);
}

// ---------------- last-resort direct kernel (no ws) ----------------
__global__ __launch_bounds__(256) void direct_kernel(
    const float* __restrict__ x,
    const float* __restrict__ grid3d, const float* __restrict__ p0,
    const float* __restrict__ p1, const float* __restrict__ p2,
    const float* __restrict__ line0, float* __restrict__ out, int N)
{
    int n = blockIdx.x * blockDim.x + threadIdx.x;
    if (n >= N) return;
    float4 xv = reinterpret_cast<const float4*>(x)[n];
    Axis gx = make_axis((xv.x + 1.0f) * 0.5f * 127.0f, 128);
    Axis gy = make_axis((xv.y + 1.0f) * 0.5f * 127.0f, 128);
    Axis gz = make_axis((xv.z + 1.0f) * 0.5f * 127.0f, 128);
    Axis q0 = make_axis((xv.x + 1.0f) * 0.5f * 255.0f, 256);
    Axis q1 = make_axis((xv.y + 1.0f) * 0.5f * 255.0f, 256);
    Axis q2 = make_axis((xv.z + 1.0f) * 0.5f * 255.0f, 256);
    Axis lx = make_axis(xv.w * 63.0f, 64);
    const int GS = 128 * 128 * 128, PS = 256 * 256, ZS = 128 * 128;
    int gb  = (gz.base * 128 + gy.base) * 128 + gx.base;
    int b0b = q2.base * 256 + q1.base;
    int b1b = q2.base * 256 + q0.base;
    int b2b = q1.base * 256 + q0.base;
    float res[32];
    #pragma unroll
    for (int c = 0; c < 16; ++c) {
        const float* g = grid3d + c * GS + gb;
        float d00 = g[0]        * gx.u0 + g[1]        * gx.u1;
        float d01 = g[128]      * gx.u0 + g[129]      * gx.u1;
        float d10 = g[ZS]       * gx.u0 + g[ZS + 1]   * gx.u1;
        float d11 = g[ZS + 128] * gx.u0 + g[ZS + 129] * gx.u1;
        float tri = gz.u0 * (gy.u0 * d00 + gy.u1 * d01)
                  + gz.u1 * (gy.u0 * d10 + gy.u1 * d11);
        const float* a = p0 + c * PS + b0b;
        float v0 = q2.u0 * (a[0] * q1.u0 + a[1] * q1.u1)
                 + q2.u1 * (a[256] * q1.u0 + a[257] * q1.u1);
        const float* b = p1 + c * PS + b1b;
        float v1 = q2.u0 * (b[0] * q0.u0 + b[1] * q0.u1)
                 + q2.u1 * (b[256] * q0.u0 + b[257] * q0.u1);
        const float* d = p2 + c * PS + b2b;
        float v2 = q1.u0 * (d[0] * q0.u0 + d[1] * q0.u1)
                 + q1.u1 * (d[256] * q0.u0 + d[257] * q0.u1);
        const float* ln = line0 + c * 64 + lx.base;
        res[16 + c] = ln[0] * lx.u0 + ln[1] * lx.u1;
        res[c]      = tri * v0 * v1 * v2;
    }
    float4* o4 = reinterpret_cast<float4*>(out + (size_t)n * 32);
    #pragma unroll
    for (int i = 0; i < 8; ++i)
        o4[i] = make_float4(res[i*4], res[i*4+1], res[i*4+2], res[i*4+3]);
}

extern "C" void kernel_launch(void* const* d_in, const int* in_sizes, int n_in,
                              void* d_out, int out_size, void* d_ws, size_t ws_size,
                              hipStream_t stream) {
    const float* x      = (const float*)d_in[0];
    const float* grid3d = (const float*)d_in[1];
    const float* p0     = (const float*)d_in[2];
    const float* p1     = (const float*)d_in[3];
    const float* p2     = (const float*)d_in[4];
    const float* line0  = (const float*)d_in[5];
    float* out = (float*)d_out;
    int N = in_sizes[0] / 4;

    size_t tab_off   = 0;
    size_t ghist_off = align256(WS_HALVES * sizeof(__half));
    size_t gbase_off = ghist_off + (size_t)NZB * NBLK * 4;
    size_t sx_off    = align256(gbase_off + (size_t)NZB * NBLK * 4);
    size_t sidx_off  = sx_off + (size_t)N * 16;
    size_t need_sort = sidx_off + (size_t)N * 4;
    size_t need_tab  = WS_HALVES * sizeof(__half);

    if (ws_size >= need_sort) {
        char* wsb = (char*)d_ws;
        __half* tab   = (__half*)(wsb + tab_off);
        int*    ghist = (int*)(wsb + ghist_off);
        int*    gbase = (int*)(wsb + gbase_off);
        float4* sxp   = (float4*)(wsb + sx_off);
        int*    sidx  = (int*)(wsb + sidx_off);
        const float4* x4 = (const float4*)x;
        int chunk = (N + NBLK - 1) / NBLK;

        relayout_kernel<<<(int)((WS_HALVES + 255) / 256), 256, 0, stream>>>(
            grid3d, p0, p1, p2, line0, tab);
        hist_kernel<<<NBLK, 256, 0, stream>>>(x4, ghist, N, chunk);
        offsets_kernel<<<1, 64, 0, stream>>>(ghist, gbase);
        scatter_kernel<<<NBLK, 256, 0, stream>>>(x4, gbase, sxp, sidx, N, chunk);
        int blocks = (N + 127) / 128;
        sample_sorted_kernel<<<blocks, 256, 0, stream>>>(sxp, sidx, tab, out, N);
    } else if (ws_size >= need_tab) {
        __half* tab = (__half*)d_ws;
        relayout_kernel<<<(int)((WS_HALVES + 255) / 256), 256, 0, stream>>>(
            grid3d, p0, p1, p2, line0, tab);
        long long tot = (long long)N * 2;
        sample_unsorted_kernel<<<(int)((tot + 255) / 256), 256, 0, stream>>>(
            x, tab, out, N);
    } else {
        direct_kernel<<<(N + 255) / 256, 256, 0, stream>>>(
            x, grid3d, p0, p1, p2, line0, out, N);
    }
}